// Round 10
// baseline (27.238 us; speedup 1.0000x reference)
//
#include <hip/hip_runtime.h>

#define BATCH  4096
#define NCTRL  64
#define SDIM   2048
#define WSZ    64                // 1 wave per block
#define VPT    4                 // consecutive samples per lane per chunk
#define CHUNK  (WSZ * VPT)       // 256 samples per chunk
#define NCHUNK 4                 // chunks per block (1024 samples/block)
#define NXCD   8

__global__ __launch_bounds__(WSZ, 8) void curve_eval_kernel(
    const float4* __restrict__ cp,     // [B, NCTRL] as float4 (x,y,z,w)
    const int*    __restrict__ span,   // [SDIM]
    const float4* __restrict__ basis,  // [SDIM] as float4
    float4*       __restrict__ out)    // [B,SDIM,3] f32 viewed as float4
{
    __shared__ float4 cp_s[NCTRL + 1];           // +1 pad row for sp0+1 window
    __shared__ float4 out_s4[CHUNK * 3 / 4];     // 3 KB staging, reused per chunk

    // XCD-local remap: x = wg&7 (round-robin XCD), each XCD owns a contiguous
    // 512-curve slab; 2 blocks per curve (halves). cp stays L2-local per XCD.
    const int wg   = blockIdx.x;
    const int x    = wg & (NXCD - 1);
    const int i    = wg >> 3;                    // 0..1023 per XCD
    const int b    = x * (BATCH / NXCD) + (i >> 1);
    const int s0b  = (i & 1) * (CHUNK * NCHUNK); // 0 or 1024
    const int tid  = threadIdx.x;                // 0..63

    // Stage curve ONCE for 4 chunks: 1 global b128 + 1 ds_write_b128 per lane.
    const float4 cpv = cp[(size_t)b * NCTRL + tid];
    cp_s[tid] = cpv;
    if (tid == NCTRL - 1) cp_s[NCTRL] = cpv;     // pad (weight 0 when read)
    __syncthreads();

    for (int c = 0; c < NCHUNK; ++c) {
        const int s0 = s0b + c * CHUNK;

        // Lane's 4 consecutive samples: span boundary spacing ~33 samples ->
        // spans within the window are sp0 or sp0+1.
        const int  sbase = s0 + tid * VPT;
        const int4 sp4   = reinterpret_cast<const int4*>(span)[(s0 >> 2) + tid];
        const int  sp0   = sp4.x;
        const int  spk[VPT] = {sp4.x, sp4.y, sp4.z, sp4.w};

        // One 5-row window serves all 4 samples: 5 ds_read_b128.
        float4 rows[5];
        #pragma unroll
        for (int j = 0; j < 5; ++j) rows[j] = cp_s[sp0 - 3 + j];

        float o[VPT * 3];
        #pragma unroll
        for (int k = 0; k < VPT; ++k) {
            const float4 bas = basis[sbase + k];   // L1-resident (32 KB total)
            const bool hi = (spk[k] > sp0);        // shift basis one row down
            const float w0 = hi ? 0.0f  : bas.x;
            const float w1 = hi ? bas.x : bas.y;
            const float w2 = hi ? bas.y : bas.z;
            const float w3 = hi ? bas.z : bas.w;
            const float w4 = hi ? bas.w : 0.0f;

            const float xx = w0*rows[0].x + w1*rows[1].x + w2*rows[2].x + w3*rows[3].x + w4*rows[4].x;
            const float yy = w0*rows[0].y + w1*rows[1].y + w2*rows[2].y + w3*rows[3].y + w4*rows[4].y;
            const float zz = w0*rows[0].z + w1*rows[1].z + w2*rows[2].z + w3*rows[3].z + w4*rows[4].z;
            const float ww = w0*rows[0].w + w1*rows[1].w + w2*rows[2].w + w3*rows[3].w + w4*rows[4].w;

            const float invw = __builtin_amdgcn_rcpf(ww);  // 5x headroom vs thr
            o[k * 3 + 0] = xx * invw;
            o[k * 3 + 1] = yy * invw;
            o[k * 3 + 2] = zz * invw;
        }

        // 12 contiguous floats -> 3 ds_write_b128 at 48B stride (conflict-free).
        float4* mine = &out_s4[tid * 3];
        mine[0] = make_float4(o[0], o[1],  o[2],  o[3]);
        mine[1] = make_float4(o[4], o[5],  o[6],  o[7]);
        mine[2] = make_float4(o[8], o[9],  o[10], o[11]);
        __syncthreads();   // 1-wave block: ~free; orders ds_write -> ds_read

        // Coalesced flush: 64 lanes x 16B fully contiguous per instruction.
        // Next iteration's ds_writes can't pass these ds_reads (in-order DS).
        const size_t base4 = ((size_t)b * SDIM + (size_t)s0) * 3u / 4u;
        #pragma unroll
        for (int k = 0; k < 3; ++k) {
            out[base4 + tid + k * WSZ] = out_s4[tid + k * WSZ];
        }
    }
}

extern "C" void kernel_launch(void* const* d_in, const int* in_sizes, int n_in,
                              void* d_out, int out_size, void* d_ws, size_t ws_size,
                              hipStream_t stream) {
    const float4* cp    = (const float4*)d_in[0];  // [4096,64,4] f32
    const int*    span  = (const int*)d_in[1];     // [2048] i32
    const float4* basis = (const float4*)d_in[2];  // [2048,4] f32
    float4*       out   = (float4*)d_out;          // [4096,2048,3] f32

    const int nblocks = BATCH * SDIM / (CHUNK * NCHUNK);   // 8192 one-wave blocks
    curve_eval_kernel<<<nblocks, WSZ, 0, stream>>>(cp, span, basis, out);
}

// Round 11
// 24.214 us; speedup vs baseline: 1.1249x; 1.1249x over previous
//
#include <hip/hip_runtime.h>

#define BATCH  4096
#define NCTRL  64
#define SDIM   2048
#define BLK    256               // 4 waves per block
#define WSZ    64
#define NWAVE  (BLK / WSZ)
#define VPT    4                 // consecutive samples per lane
#define CHUNK  (WSZ * VPT)       // 256 samples per wave
#define NXCD   8

__global__ __launch_bounds__(BLK, 8) void curve_eval_kernel(
    const float4* __restrict__ cp,     // [B, NCTRL] as float4 (x,y,z,w)
    const int*    __restrict__ span,   // [SDIM]
    const float4* __restrict__ basis,  // [SDIM] as float4
    float4*       __restrict__ out)    // [B,SDIM,3] f32 viewed as float4
{
    __shared__ float4 cp_s[NCTRL + 1];                    // 1 KB + pad
    __shared__ float4 out_s4[NWAVE * CHUNK * 3 / 4];      // 12 KB, per-wave regions

    // XCD-local remap: x = wg&7 round-robins XCDs; each XCD owns a contiguous
    // 512-curve slab; 2 blocks per curve (halves), consecutive -> same XCD.
    const int wg   = blockIdx.x;
    const int x    = wg & (NXCD - 1);
    const int i    = wg >> 3;                    // 0..1023 per XCD
    const int b    = x * (BATCH / NXCD) + (i >> 1);
    const int s0b  = (i & 1) * (NWAVE * CHUNK);  // 0 or 1024
    const int tid  = threadIdx.x;                // 0..255
    const int wid  = tid >> 6;                   // wave 0..3
    const int lane = tid & (WSZ - 1);            // 0..63

    // Stage curve once per block: wave 0's lanes load 64 rows.
    if (tid < NCTRL) {
        const float4 cpv = cp[(size_t)b * NCTRL + tid];
        cp_s[tid] = cpv;
        if (tid == NCTRL - 1) cp_s[NCTRL] = cpv;          // pad (weight 0 unused)
    }
    __syncthreads();   // ONLY block-wide barrier; waves decouple after this

    // Each wave owns one 256-sample chunk; block covers 1024 contiguous samples.
    const int s0    = s0b + wid * CHUNK;
    const int sbase = s0 + lane * VPT;
    const int4 sp4  = reinterpret_cast<const int4*>(span)[(s0 >> 2) + lane];
    const int  sp0  = sp4.x;
    const int  spk[VPT] = {sp4.x, sp4.y, sp4.z, sp4.w};

    // One 5-row window serves all 4 samples: 5 ds_read_b128.
    float4 rows[5];
    #pragma unroll
    for (int j = 0; j < 5; ++j) rows[j] = cp_s[sp0 - 3 + j];

    float o[VPT * 3];
    #pragma unroll
    for (int k = 0; k < VPT; ++k) {
        const float4 bas = basis[sbase + k];     // L1-resident (32 KB total)
        const bool hi = (spk[k] > sp0);          // shift basis one row down
        const float w0 = hi ? 0.0f  : bas.x;
        const float w1 = hi ? bas.x : bas.y;
        const float w2 = hi ? bas.y : bas.z;
        const float w3 = hi ? bas.z : bas.w;
        const float w4 = hi ? bas.w : 0.0f;

        const float xx = w0*rows[0].x + w1*rows[1].x + w2*rows[2].x + w3*rows[3].x + w4*rows[4].x;
        const float yy = w0*rows[0].y + w1*rows[1].y + w2*rows[2].y + w3*rows[3].y + w4*rows[4].y;
        const float zz = w0*rows[0].z + w1*rows[1].z + w2*rows[2].z + w3*rows[3].z + w4*rows[4].z;
        const float ww = w0*rows[0].w + w1*rows[1].w + w2*rows[2].w + w3*rows[3].w + w4*rows[4].w;

        const float invw = __builtin_amdgcn_rcpf(ww);   // 5x headroom vs threshold
        o[k * 3 + 0] = xx * invw;
        o[k * 3 + 1] = yy * invw;
        o[k * 3 + 2] = zz * invw;
    }

    // Per-wave transpose through this wave's private LDS region. 48B lane
    // stride -> conflict-free banks.
    float4* region = &out_s4[wid * (CHUNK * 3 / 4)];
    float4* mine   = &region[lane * 3];
    mine[0] = make_float4(o[0], o[1],  o[2],  o[3]);
    mine[1] = make_float4(o[4], o[5],  o[6],  o[7]);
    mine[2] = make_float4(o[8], o[9],  o[10], o[11]);

    // Wave-local ordering: drain ds_writes, then read back transposed.
    // No __syncthreads -> the 4 waves stay phase-decoupled.
    asm volatile("s_waitcnt lgkmcnt(0)" ::: "memory");

    // Coalesced flush: 3 instrs x (64 lanes x 16B) contiguous = 3 KB per wave.
    const size_t base4 = ((size_t)b * SDIM + (size_t)s0) * 3u / 4u;
    #pragma unroll
    for (int k = 0; k < 3; ++k) {
        out[base4 + lane + k * WSZ] = region[lane + k * WSZ];
    }
}

extern "C" void kernel_launch(void* const* d_in, const int* in_sizes, int n_in,
                              void* d_out, int out_size, void* d_ws, size_t ws_size,
                              hipStream_t stream) {
    const float4* cp    = (const float4*)d_in[0];  // [4096,64,4] f32
    const int*    span  = (const int*)d_in[1];     // [2048] i32
    const float4* basis = (const float4*)d_in[2];  // [2048,4] f32
    float4*       out   = (float4*)d_out;          // [4096,2048,3] f32

    const int nblocks = BATCH * SDIM / (NWAVE * CHUNK);   // 8192 4-wave blocks
    curve_eval_kernel<<<nblocks, BLK, 0, stream>>>(cp, span, basis, out);
}